// Round 4
// baseline (1706.880 us; speedup 1.0000x reference)
//
#include <hip/hip_runtime.h>
#include <hip/hip_cooperative_groups.h>

namespace cg = cooperative_groups;

#define BB 8192
#define TT 10
#define FF 561
#define FP 576   // 561 padded to 18*32
#define HH 256
#define OO 12

typedef __attribute__((ext_vector_type(8))) __bf16 bf16x8;
typedef __attribute__((ext_vector_type(4))) float f32x4;

__device__ __forceinline__ unsigned short f2bf(float f) {
  unsigned int u = __float_as_uint(f);
  u += 0x7fffu + ((u >> 16) & 1u);   // round-to-nearest-even
  return (unsigned short)(u >> 16);
}
__device__ __forceinline__ float sigm(float x) { return 1.f / (1.f + __expf(-x)); }
__device__ __forceinline__ float tanh_fast(float x) { return 1.f - 2.f / (__expf(2.f * x) + 1.f); }

__device__ __forceinline__ void gl_lds16(const unsigned short* g, unsigned short* l) {
  __builtin_amdgcn_global_load_lds(
      (const __attribute__((address_space(1))) unsigned int*)g,
      (__attribute__((address_space(3))) unsigned int*)l, 16, 0, 0);
}
__device__ __forceinline__ void gl_lds4(const float* g, float* l) {
  __builtin_amdgcn_global_load_lds(
      (const __attribute__((address_space(1))) unsigned int*)g,
      (__attribute__((address_space(3))) unsigned int*)l, 4, 0, 0);
}

// 8 f32 (LDS) -> bf16x8 fragment
__device__ __forceinline__ bf16x8 cvt8(const float* fp) {
  f32x4 x0 = *(const f32x4*)fp;
  f32x4 x1 = *(const f32x4*)(fp + 4);
  union { bf16x8 v; unsigned short s[8]; } u;
  u.s[0] = f2bf(x0[0]); u.s[1] = f2bf(x0[1]); u.s[2] = f2bf(x0[2]); u.s[3] = f2bf(x0[3]);
  u.s[4] = f2bf(x1[0]); u.s[5] = f2bf(x1[1]); u.s[6] = f2bf(x1[2]); u.s[7] = f2bf(x1[3]);
  return u.v;
}

// Build bf16 weights:
//  Wib [256][576]: W_inp zero-padded (cols 561.. are ZERO -> xp A-clamp trick)
//  W0p/W1p [1024][512]: permuted fused [Wih|Whh];
//    out row n' -> (h=(n'>>7)*32+(n'&31), gate=(n'>>5)&3), src row = gate*256+h
//  Wob [16][256]: W_out zero-padded rows 12..15
__global__ void conv_weights(const float* __restrict__ Winp,
                             const float* __restrict__ Wih0, const float* __restrict__ Whh0,
                             const float* __restrict__ Wih1, const float* __restrict__ Whh1,
                             const float* __restrict__ Wout,
                             unsigned short* __restrict__ Wib,
                             unsigned short* __restrict__ W0p,
                             unsigned short* __restrict__ W1p,
                             unsigned short* __restrict__ Wob) {
  int idx = blockIdx.x * 256 + threadIdx.x;
  if (idx < 256 * 576) {
    int kk = idx % 576, n = idx / 576;
    Wib[idx] = f2bf(kk < 561 ? Winp[n * 561 + kk] : 0.f);
    return;
  }
  idx -= 256 * 576;
  if (idx < 1024 * 512) {
    int kk = idx % 512, np = idx / 512;
    int h = (np >> 7) * 32 + (np & 31), g = (np >> 5) & 3;
    int sr = g * 256 + h;
    float v = kk < 256 ? Wih0[sr * 256 + kk] : Whh0[sr * 256 + kk - 256];
    W0p[idx] = f2bf(v);
    return;
  }
  idx -= 1024 * 512;
  if (idx < 1024 * 512) {
    int kk = idx % 512, np = idx / 512;
    int h = (np >> 7) * 32 + (np & 31), g = (np >> 5) & 3;
    int sr = g * 256 + h;
    float v = kk < 256 ? Wih1[sr * 256 + kk] : Whh1[sr * 256 + kk - 256];
    W1p[idx] = f2bf(v);
    return;
  }
  idx -= 1024 * 512;
  if (idx < 16 * 256) {
    int kk = idx % 256, o = idx / 256;
    Wob[idx] = f2bf(o < OO ? Wout[o * 256 + kk] : 0.f);
  }
}

// xp[81920][256] = bf16( f32 inputs [81920][561] ) @ Wib^T + b_inp
// Fused convert: A staged as f32 via gl_lds width-4 (rows only 4B-aligned),
// converted to bf16 frags at LDS->reg time. K cols >=561 read clamped addr;
// Wib's zero cols null them out. Mt=128, Nt=256(all), 512 thr, 8 waves (4x2).
__global__ __launch_bounds__(512, 2) void xp_gemm(
    const float* __restrict__ in,
    const unsigned short* __restrict__ Wib,
    const float* __restrict__ binp,
    unsigned short* __restrict__ xp) {
  __shared__ __align__(16) float Af[2][128 * 32];
  __shared__ __align__(16) unsigned short Bs[2][256 * 32];
  const int tid = threadIdx.x;
  const int w = tid >> 6, lane = tid & 63, quad = lane >> 4, l15 = lane & 15;
  const int wr = w & 3, wc = w >> 2;
  const int mb = blockIdx.x;
  const int ar = tid >> 5, acl = tid & 31;      // A staging: 16 rows/issue, 1 dword each
  const int sr = tid >> 2, sc = (tid & 3) * 8;  // B staging: 16B chunks

  auto stage = [&](int k0, int buf) {
#pragma unroll
    for (int ii = 0; ii < 8; ++ii) {
      int row = mb * 128 + ii * 16 + ar;
      int col = k0 + acl; col = col < FF ? col : FF - 1;
      gl_lds4(in + (size_t)row * FF + col, &Af[buf][(ii * 16 + ar) * 32 + acl]);
    }
    const unsigned short* g1 = Wib + (size_t)sr * FP + k0 + sc;
    gl_lds16(g1, &Bs[buf][tid * 8]);
    gl_lds16(g1 + (size_t)128 * FP, &Bs[buf][4096 + tid * 8]);
  };

  f32x4 acc[2][8];
#pragma unroll
  for (int i = 0; i < 2; ++i)
#pragma unroll
    for (int j = 0; j < 8; ++j) acc[i][j] = (f32x4){0.f, 0.f, 0.f, 0.f};

  stage(0, 0);
  __syncthreads();
  int pb = 0;
  for (int k0 = 0; k0 < FP; k0 += 32) {
    if (k0 + 32 < FP) stage(k0 + 32, pb ^ 1);
    bf16x8 af[2], bfr[8];
#pragma unroll
    for (int mt = 0; mt < 2; ++mt)
      af[mt] = cvt8(&Af[pb][(wr * 32 + mt * 16 + l15) * 32 + quad * 8]);
#pragma unroll
    for (int nt = 0; nt < 8; ++nt)
      bfr[nt] = *(const bf16x8*)&Bs[pb][(wc * 128 + nt * 16 + l15) * 32 + quad * 8];
#pragma unroll
    for (int mt = 0; mt < 2; ++mt)
#pragma unroll
      for (int nt = 0; nt < 8; ++nt)
        acc[mt][nt] = __builtin_amdgcn_mfma_f32_16x16x32_bf16(af[mt], bfr[nt], acc[mt][nt], 0, 0, 0);
    __syncthreads();
    pb ^= 1;
  }

#pragma unroll
  for (int mt = 0; mt < 2; ++mt) {
    int rowb = mb * 128 + wr * 32 + mt * 16 + quad * 4;
#pragma unroll
    for (int nt = 0; nt < 8; ++nt) {
      int col = wc * 128 + nt * 16 + l15;
      float bv = binp[col];
#pragma unroll
      for (int r = 0; r < 4; ++r)
        xp[(size_t)(rowb + r) * HH + col] = f2bf(acc[mt][nt][r] + bv);
    }
  }
}

// Persistent pipelined recurrence. 256 blocks x 512 threads, cooperative.
// 11 phases p=0..10: blocks[group=0] do layer0 step t=p (p<10);
// blocks[group=1] do layer1 step t=p-1 (p>=1). grid.sync() between phases.
// Per block: Mt=256 x Nt=256 tile of the M=8192 x N=1024(gate-permuted) GEMM,
// K=512 dual-source ([x | h_prev]). 8 waves as 4x2: wave = 64 rows x 128 cols.
// XCD swizzle: xcd=blockIdx&7; group=xcd>>2; mb spread so each XCD reuses
// its W tiles and A rows in local L2.
__global__ __launch_bounds__(512, 2) void lstm_recurrence(
    const unsigned short* __restrict__ xp,   // [B][T][H] bf16
    const unsigned short* __restrict__ W0p,  // [1024][512]
    const unsigned short* __restrict__ W1p,
    const float* __restrict__ bih0, const float* __restrict__ bhh0,
    const float* __restrict__ bih1, const float* __restrict__ bhh1,
    unsigned short* __restrict__ h0s,        // [2][B][H] ping-pong, slot0 zeroed
    unsigned short* __restrict__ hs,         // [T+1][B][H], slot0 zeroed
    float* __restrict__ c0, float* __restrict__ c1,  // zeroed
    float* __restrict__ hn_out, float* __restrict__ cn_out) {
  __shared__ __align__(16) unsigned short As[2][256 * 32];
  __shared__ __align__(16) unsigned short Bs[2][256 * 32];
  cg::grid_group gg = cg::this_grid();

  const int tid = threadIdx.x;
  const int w = tid >> 6, lane = tid & 63, quad = lane >> 4, l15 = lane & 15;
  const int wr = w & 3, wc = w >> 2;
  const int i = blockIdx.x;
  const int xcd = i & 7, slot = i >> 3;          // 32 slots per xcd
  const int group = xcd >> 2;                    // 0: layer0, 1: layer1
  const int mb = (xcd & 3) * 8 + (slot >> 2);    // 0..31
  const int nb = slot & 3;                       // 0..3

  const unsigned short* W = group ? W1p : W0p;
  const float* bA = group ? bih1 : bih0;
  const float* bB = group ? bhh1 : bhh0;
  float* cbuf = group ? c1 : c0;

  const int sr = tid >> 2, sc = (tid & 3) * 8;   // staging: 16B chunks

  for (int p = 0; p <= TT; ++p) {
    const bool active = group ? (p >= 1) : (p < TT);
    if (active) {
      const int t = group ? p - 1 : p;
      const unsigned short* A0;
      int lda0;
      if (group) { A0 = h0s + (size_t)(p & 1) * BB * HH; lda0 = HH; }
      else       { A0 = xp + (size_t)t * HH;             lda0 = TT * HH; }
      const unsigned short* A1 = group ? (hs + (size_t)t * BB * HH)
                                       : (h0s + (size_t)(p & 1) * BB * HH);

      auto stageA = [&](int k0, int buf) {
        const unsigned short* Asrc;
        int ldA, kk;
        if (k0 < 256) { Asrc = A0; ldA = lda0; kk = k0; }
        else          { Asrc = A1; ldA = HH;   kk = k0 - 256; }
        const unsigned short* g0 = Asrc + (size_t)(mb * 256 + sr) * ldA + kk + sc;
        gl_lds16(g0, &As[buf][tid * 8]);
        gl_lds16(g0 + (size_t)128 * ldA, &As[buf][4096 + tid * 8]);
        const unsigned short* g1 = W + (size_t)(nb * 256 + sr) * 512 + k0 + sc;
        gl_lds16(g1, &Bs[buf][tid * 8]);
        gl_lds16(g1 + (size_t)128 * 512, &Bs[buf][4096 + tid * 8]);
      };

      f32x4 acc[4][8];
#pragma unroll
      for (int a = 0; a < 4; ++a)
#pragma unroll
        for (int b = 0; b < 8; ++b) acc[a][b] = (f32x4){0.f, 0.f, 0.f, 0.f};

      stageA(0, 0);
      __syncthreads();
      int pb = 0;
      for (int k0 = 0; k0 < 512; k0 += 32) {
        if (k0 + 32 < 512) stageA(k0 + 32, pb ^ 1);
        bf16x8 af[4], bfr[8];
#pragma unroll
        for (int mt = 0; mt < 4; ++mt)
          af[mt] = *(const bf16x8*)&As[pb][(wr * 64 + mt * 16 + l15) * 32 + quad * 8];
#pragma unroll
        for (int nt = 0; nt < 8; ++nt)
          bfr[nt] = *(const bf16x8*)&Bs[pb][(wc * 128 + nt * 16 + l15) * 32 + quad * 8];
#pragma unroll
        for (int mt = 0; mt < 4; ++mt)
#pragma unroll
          for (int nt = 0; nt < 8; ++nt)
            acc[mt][nt] = __builtin_amdgcn_mfma_f32_16x16x32_bf16(af[mt], bfr[nt], acc[mt][nt], 0, 0, 0);
        __syncthreads();
        pb ^= 1;
      }

      // fused LSTM cell epilogue. Wave's 128 cols = h-group (2nb+wc)*32..+32, 4 gates.
      unsigned short* hout = group ? (hs + (size_t)(t + 1) * BB * HH)
                                   : (h0s + (size_t)((p + 1) & 1) * BB * HH);
      float* hf = nullptr; float* cf = nullptr;
      if (t == TT - 1) {
        hf = hn_out + (group ? (size_t)BB * HH : 0);
        cf = cn_out + (group ? (size_t)BB * HH : 0);
      }
      const int hg32 = (2 * nb + wc) * 32;
#pragma unroll
      for (int hb = 0; hb < 2; ++hb) {
        const int hgl = hg32 + hb * 16 + l15;
        float bI = bA[hgl] + bB[hgl];
        float bF = bA[256 + hgl] + bB[256 + hgl];
        float bG = bA[512 + hgl] + bB[512 + hgl];
        float bO = bA[768 + hgl] + bB[768 + hgl];
#pragma unroll
        for (int mt = 0; mt < 4; ++mt) {
          const int rowb = mb * 256 + wr * 64 + mt * 16 + quad * 4;
#pragma unroll
          for (int r = 0; r < 4; ++r) {
            const size_t idx = (size_t)(rowb + r) * HH + hgl;
            float xi = acc[mt][0 + hb][r] + bI;
            float xf = acc[mt][2 + hb][r] + bF;
            float xg = acc[mt][4 + hb][r] + bG;
            float xo = acc[mt][6 + hb][r] + bO;
            float c_old = cbuf[idx];
            float cn = sigm(xf) * c_old + sigm(xi) * tanh_fast(xg);
            float hn = sigm(xo) * tanh_fast(cn);
            cbuf[idx] = cn;
            hout[idx] = f2bf(hn);
            if (hf) hf[idx] = hn;
            if (cf) cf[idx] = cn;
          }
        }
      }
    }
    if (p < TT) {
      __threadfence();   // device-scope: make h/c stores visible cross-XCD
      gg.sync();
    }
  }
}

// Output projection: out[m=t*B+b][o] = hs[m+B][:] . Wob[o][:] + bout[o]
// M=81920, N=16 (12 used), K=256. One 16x16 tile per wave.
__global__ __launch_bounds__(256) void out_gemm_mfma(
    const unsigned short* __restrict__ hs,
    const unsigned short* __restrict__ Wob,
    const float* __restrict__ bout,
    float* __restrict__ out) {
  const int tid = threadIdx.x;
  const int w = tid >> 6, lane = tid & 63, quad = lane >> 4, l15 = lane & 15;
  const int m0 = blockIdx.x * 64 + w * 16;
  const unsigned short* arow = hs + (size_t)(m0 + l15 + BB) * HH + quad * 8;
  const unsigned short* brow = Wob + l15 * HH + quad * 8;
  f32x4 acc = (f32x4){0.f, 0.f, 0.f, 0.f};
#pragma unroll
  for (int k0 = 0; k0 < 8; ++k0) {
    bf16x8 a = *(const bf16x8*)(arow + k0 * 32);
    bf16x8 b = *(const bf16x8*)(brow + k0 * 32);
    acc = __builtin_amdgcn_mfma_f32_16x16x32_bf16(a, b, acc, 0, 0, 0);
  }
  const int o = l15;
  if (o < OO) {
    float bv = bout[o];
#pragma unroll
    for (int r = 0; r < 4; ++r) {
      int m = m0 + quad * 4 + r;
      int b = m & (BB - 1);
      int t = m >> 13;
      out[((size_t)b * TT + t) * OO + o] = acc[r] + bv;
    }
  }
}

extern "C" void kernel_launch(void* const* d_in, const int* in_sizes, int n_in,
                              void* d_out, int out_size, void* d_ws, size_t ws_size,
                              hipStream_t stream) {
  const float* inputs = (const float*)d_in[0];
  const float* W_inp  = (const float*)d_in[1];
  const float* b_inp  = (const float*)d_in[2];
  const float* Wih0   = (const float*)d_in[3];
  const float* Whh0   = (const float*)d_in[4];
  const float* bih0   = (const float*)d_in[5];
  const float* bhh0   = (const float*)d_in[6];
  const float* Wih1   = (const float*)d_in[7];
  const float* Whh1   = (const float*)d_in[8];
  const float* bih1   = (const float*)d_in[9];
  const float* bhh1   = (const float*)d_in[10];
  const float* W_out  = (const float*)d_in[11];
  const float* b_out  = (const float*)d_in[12];
  float* out = (float*)d_out;

  char* ws = (char*)d_ws;
  size_t off = 0;
  auto alloc = [&](size_t bytes) {
    char* p = ws + off;
    off += (bytes + 255) & ~(size_t)255;
    return p;
  };
  unsigned short* xp  = (unsigned short*)alloc((size_t)81920 * HH * 2);
  unsigned short* Wib = (unsigned short*)alloc((size_t)256 * FP * 2);
  unsigned short* W0p = (unsigned short*)alloc((size_t)1024 * 512 * 2);
  unsigned short* W1p = (unsigned short*)alloc((size_t)1024 * 512 * 2);
  unsigned short* Wob = (unsigned short*)alloc((size_t)16 * HH * 2);
  unsigned short* h0s = (unsigned short*)alloc((size_t)2 * BB * HH * 2);
  unsigned short* hs  = (unsigned short*)alloc((size_t)(TT + 1) * BB * HH * 2);
  float* c0 = (float*)alloc((size_t)BB * HH * 4);
  float* c1 = (float*)alloc((size_t)BB * HH * 4);

  hipMemsetAsync(h0s, 0, (size_t)BB * HH * 2, stream);   // slot 0 only
  hipMemsetAsync(hs, 0, (size_t)BB * HH * 2, stream);    // slot 0 only
  hipMemsetAsync(c0, 0, (size_t)BB * HH * 4, stream);
  hipMemsetAsync(c1, 0, (size_t)BB * HH * 4, stream);

  {
    int nthr = 256 * 576 + 2 * 1024 * 512 + 16 * 256;
    conv_weights<<<(nthr + 255) / 256, 256, 0, stream>>>(W_inp, Wih0, Whh0, Wih1, Whh1,
                                                         W_out, Wib, W0p, W1p, Wob);
  }

  xp_gemm<<<640, 512, 0, stream>>>(inputs, Wib, b_inp, xp);

  float* hn_out = out + (size_t)BB * TT * OO;       // h_n [2][B][H]
  float* cn_out = hn_out + (size_t)2 * BB * HH;     // c_n [2][B][H]

  {
    void* args[] = {(void*)&xp, (void*)&W0p, (void*)&W1p,
                    (void*)&bih0, (void*)&bhh0, (void*)&bih1, (void*)&bhh1,
                    (void*)&h0s, (void*)&hs, (void*)&c0, (void*)&c1,
                    (void*)&hn_out, (void*)&cn_out};
    hipLaunchCooperativeKernel((void*)lstm_recurrence, dim3(256), dim3(512),
                               args, 0, stream);
  }

  out_gemm_mfma<<<1280, 256, 0, stream>>>(hs, Wob, b_out, out);
}

// Round 5
// 888.400 us; speedup vs baseline: 1.9213x; 1.9213x over previous
//
#include <hip/hip_runtime.h>

#define BB 8192
#define TT 10
#define FF 561
#define FP 576   // 561 padded to 18*32
#define HH 256
#define OO 12

typedef __attribute__((ext_vector_type(8))) __bf16 bf16x8;
typedef __attribute__((ext_vector_type(4))) float f32x4;

__device__ __forceinline__ unsigned short f2bf(float f) {
  unsigned int u = __float_as_uint(f);
  u += 0x7fffu + ((u >> 16) & 1u);   // round-to-nearest-even
  return (unsigned short)(u >> 16);
}
__device__ __forceinline__ float sigm(float x) { return 1.f / (1.f + __expf(-x)); }
__device__ __forceinline__ float tanh_fast(float x) { return 1.f - 2.f / (__expf(2.f * x) + 1.f); }

__device__ __forceinline__ void gl_lds16(const unsigned short* g, unsigned short* l) {
  __builtin_amdgcn_global_load_lds(
      (const __attribute__((address_space(1))) unsigned int*)g,
      (__attribute__((address_space(3))) unsigned int*)l, 16, 0, 0);
}
__device__ __forceinline__ void gl_lds4(const float* g, float* l) {
  __builtin_amdgcn_global_load_lds(
      (const __attribute__((address_space(1))) unsigned int*)g,
      (__attribute__((address_space(3))) unsigned int*)l, 4, 0, 0);
}

// 8 f32 (LDS) -> bf16x8 fragment
__device__ __forceinline__ bf16x8 cvt8(const float* fp) {
  f32x4 x0 = *(const f32x4*)fp;
  f32x4 x1 = *(const f32x4*)(fp + 4);
  union { bf16x8 v; unsigned short s[8]; } u;
  u.s[0] = f2bf(x0[0]); u.s[1] = f2bf(x0[1]); u.s[2] = f2bf(x0[2]); u.s[3] = f2bf(x0[3]);
  u.s[4] = f2bf(x1[0]); u.s[5] = f2bf(x1[1]); u.s[6] = f2bf(x1[2]); u.s[7] = f2bf(x1[3]);
  return u.v;
}

// Build bf16 weights:
//  Wib [256][576]: W_inp zero-padded (cols 561.. are ZERO -> xp A-clamp trick)
//  W0p/W1p [1024][512]: permuted fused [Wih|Whh];
//    out row n' -> (h=(n'>>7)*32+(n'&31), gate=(n'>>5)&3), src row = gate*256+h
//  Wob [16][256]: W_out zero-padded rows 12..15
__global__ void conv_weights(const float* __restrict__ Winp,
                             const float* __restrict__ Wih0, const float* __restrict__ Whh0,
                             const float* __restrict__ Wih1, const float* __restrict__ Whh1,
                             const float* __restrict__ Wout,
                             unsigned short* __restrict__ Wib,
                             unsigned short* __restrict__ W0p,
                             unsigned short* __restrict__ W1p,
                             unsigned short* __restrict__ Wob) {
  int idx = blockIdx.x * 256 + threadIdx.x;
  if (idx < 256 * 576) {
    int kk = idx % 576, n = idx / 576;
    Wib[idx] = f2bf(kk < 561 ? Winp[n * 561 + kk] : 0.f);
    return;
  }
  idx -= 256 * 576;
  if (idx < 1024 * 512) {
    int kk = idx % 512, np = idx / 512;
    int h = (np >> 7) * 32 + (np & 31), g = (np >> 5) & 3;
    int sr = g * 256 + h;
    float v = kk < 256 ? Wih0[sr * 256 + kk] : Whh0[sr * 256 + kk - 256];
    W0p[idx] = f2bf(v);
    return;
  }
  idx -= 1024 * 512;
  if (idx < 1024 * 512) {
    int kk = idx % 512, np = idx / 512;
    int h = (np >> 7) * 32 + (np & 31), g = (np >> 5) & 3;
    int sr = g * 256 + h;
    float v = kk < 256 ? Wih1[sr * 256 + kk] : Whh1[sr * 256 + kk - 256];
    W1p[idx] = f2bf(v);
    return;
  }
  idx -= 1024 * 512;
  if (idx < 16 * 256) {
    int kk = idx % 256, o = idx / 256;
    Wob[idx] = f2bf(o < OO ? Wout[o * 256 + kk] : 0.f);
  }
}

// xp[81920][256] = bf16( f32 inputs [81920][561] ) @ Wib^T + b_inp
// Fused convert: A staged as f32 via gl_lds width-4, converted to bf16 frags at
// LDS->reg time. K cols >=561 read clamped addr; Wib's zero cols null them out.
// Mt=128, Nt=256(all), 512 thr, 8 waves (4x2).
__global__ __launch_bounds__(512, 2) void xp_gemm(
    const float* __restrict__ in,
    const unsigned short* __restrict__ Wib,
    const float* __restrict__ binp,
    unsigned short* __restrict__ xp) {
  __shared__ __align__(16) float Af[2][128 * 32];
  __shared__ __align__(16) unsigned short Bs[2][256 * 32];
  const int tid = threadIdx.x;
  const int w = tid >> 6, lane = tid & 63, quad = lane >> 4, l15 = lane & 15;
  const int wr = w & 3, wc = w >> 2;
  const int mb = blockIdx.x;
  const int ar = tid >> 5, acl = tid & 31;      // A staging: 16 rows/issue, 1 dword each
  const int sr = tid >> 2, sc = (tid & 3) * 8;  // B staging: 16B chunks

  auto stage = [&](int k0, int buf) {
#pragma unroll
    for (int ii = 0; ii < 8; ++ii) {
      int row = mb * 128 + ii * 16 + ar;
      int col = k0 + acl; col = col < FF ? col : FF - 1;
      gl_lds4(in + (size_t)row * FF + col, &Af[buf][(ii * 16 + ar) * 32 + acl]);
    }
    const unsigned short* g1 = Wib + (size_t)sr * FP + k0 + sc;
    gl_lds16(g1, &Bs[buf][tid * 8]);
    gl_lds16(g1 + (size_t)128 * FP, &Bs[buf][4096 + tid * 8]);
  };

  f32x4 acc[2][8];
#pragma unroll
  for (int i = 0; i < 2; ++i)
#pragma unroll
    for (int j = 0; j < 8; ++j) acc[i][j] = (f32x4){0.f, 0.f, 0.f, 0.f};

  stage(0, 0);
  __syncthreads();
  int pb = 0;
  for (int k0 = 0; k0 < FP; k0 += 32) {
    if (k0 + 32 < FP) stage(k0 + 32, pb ^ 1);
    bf16x8 af[2], bfr[8];
#pragma unroll
    for (int mt = 0; mt < 2; ++mt)
      af[mt] = cvt8(&Af[pb][(wr * 32 + mt * 16 + l15) * 32 + quad * 8]);
#pragma unroll
    for (int nt = 0; nt < 8; ++nt)
      bfr[nt] = *(const bf16x8*)&Bs[pb][(wc * 128 + nt * 16 + l15) * 32 + quad * 8];
#pragma unroll
    for (int mt = 0; mt < 2; ++mt)
#pragma unroll
      for (int nt = 0; nt < 8; ++nt)
        acc[mt][nt] = __builtin_amdgcn_mfma_f32_16x16x32_bf16(af[mt], bfr[nt], acc[mt][nt], 0, 0, 0);
    __syncthreads();
    pb ^= 1;
  }

#pragma unroll
  for (int mt = 0; mt < 2; ++mt) {
    int rowb = mb * 128 + wr * 32 + mt * 16 + quad * 4;
#pragma unroll
    for (int nt = 0; nt < 8; ++nt) {
      int col = wc * 128 + nt * 16 + l15;
      float bv = binp[col];
#pragma unroll
      for (int r = 0; r < 4; ++r)
        xp[(size_t)(rowb + r) * HH + col] = f2bf(acc[mt][nt][r] + bv);
    }
  }
}

// One pipeline phase p: even blocks do layer0 step t=p (p<TT); odd blocks do
// layer1 step t=p-1 (p>=1). The two are independent; kernel boundaries provide
// all producer->consumer sync (all deps are previous-launch).
// Per block: Mt=128 x Nt=256 tile of M=8192 x N=1024(gate-permuted), K=512
// dual-source ([x | h_prev]). 512 thr, 8 waves (wr 0..3 x wc 0..1), each wave
// 32 rows x 128 cols (2x8 grid of 16x16x32 MFMA). Single-buffered LDS (R3
// showed dbuf neutral in this regime).
__global__ __launch_bounds__(512, 2) void step_pair(
    int p,
    const unsigned short* __restrict__ xp,   // [B][T][H] bf16
    const unsigned short* __restrict__ W0p,  // [1024][512]
    const unsigned short* __restrict__ W1p,
    const float* __restrict__ bih0, const float* __restrict__ bhh0,
    const float* __restrict__ bih1, const float* __restrict__ bhh1,
    unsigned short* __restrict__ h0s,        // [2][B][H] ping-pong, slot0 zeroed
    unsigned short* __restrict__ hs,         // [T+1][B][H], slot0 zeroed
    float* __restrict__ c0, float* __restrict__ c1,  // zeroed
    float* __restrict__ hn_out, float* __restrict__ cn_out) {
  const int layer = blockIdx.x & 1;
  if (layer == 0 && p >= TT) return;
  if (layer == 1 && p < 1) return;
  const int t = layer ? p - 1 : p;

  __shared__ __align__(16) unsigned short As[128 * 32];
  __shared__ __align__(16) unsigned short Bs[256 * 32];

  const int tid = threadIdx.x;
  const int w = tid >> 6, lane = tid & 63, quad = lane >> 4, l15 = lane & 15;
  const int wr = w & 3, wc = w >> 2;
  const int idx = blockIdx.x >> 1;
  const int mb = idx & 63, nb = idx >> 6;   // mb 0..63, nb 0..3

  const unsigned short* A0; int lda0;
  const unsigned short* A1;
  const unsigned short* W;
  const float *bA, *bB;
  float* cbuf;
  unsigned short* hout;
  if (layer == 0) {
    A0 = xp + (size_t)t * HH;  lda0 = TT * HH;       // xp rows stride T*H
    A1 = h0s + (size_t)(p & 1) * BB * HH;            // h0(t-1)
    W = W0p; bA = bih0; bB = bhh0; cbuf = c0;
    hout = h0s + (size_t)((p + 1) & 1) * BB * HH;
  } else {
    A0 = h0s + (size_t)(p & 1) * BB * HH; lda0 = HH; // h0(t), written prev launch
    A1 = hs + (size_t)t * BB * HH;                   // h1(t-1)
    W = W1p; bA = bih1; bB = bhh1; cbuf = c1;
    hout = hs + (size_t)(t + 1) * BB * HH;
  }

  const int sr = tid >> 2, sc = (tid & 3) * 8;       // staging: 16B chunks

  f32x4 acc[2][8];
#pragma unroll
  for (int i = 0; i < 2; ++i)
#pragma unroll
    for (int j = 0; j < 8; ++j) acc[i][j] = (f32x4){0.f, 0.f, 0.f, 0.f};

  for (int k0 = 0; k0 < 512; k0 += 32) {
    __syncthreads();
    const unsigned short* Asrc; int ldA, kk;
    if (k0 < 256) { Asrc = A0; ldA = lda0; kk = k0; }
    else          { Asrc = A1; ldA = HH;   kk = k0 - 256; }
    gl_lds16(Asrc + (size_t)(mb * 128 + sr) * ldA + kk + sc, &As[tid * 8]);
    const unsigned short* g1 = W + (size_t)(nb * 256 + sr) * 512 + k0 + sc;
    gl_lds16(g1, &Bs[tid * 8]);
    gl_lds16(g1 + (size_t)128 * 512, &Bs[4096 + tid * 8]);
    __syncthreads();

    bf16x8 af[2], bfr[8];
#pragma unroll
    for (int mt = 0; mt < 2; ++mt)
      af[mt] = *(const bf16x8*)&As[(wr * 32 + mt * 16 + l15) * 32 + quad * 8];
#pragma unroll
    for (int nt = 0; nt < 8; ++nt)
      bfr[nt] = *(const bf16x8*)&Bs[(wc * 128 + nt * 16 + l15) * 32 + quad * 8];
#pragma unroll
    for (int mt = 0; mt < 2; ++mt)
#pragma unroll
      for (int nt = 0; nt < 8; ++nt)
        acc[mt][nt] = __builtin_amdgcn_mfma_f32_16x16x32_bf16(af[mt], bfr[nt], acc[mt][nt], 0, 0, 0);
  }

  // fused LSTM cell epilogue. Wave's 128 cols = h-group (2nb+wc)*32..+32, 4 gates:
  // col bits: gate = nt>>1, h-offset = (nt&1)*16 + l15.
  float* hf = nullptr; float* cf = nullptr;
  if (t == TT - 1) {
    hf = hn_out + (layer ? (size_t)BB * HH : 0);
    cf = cn_out + (layer ? (size_t)BB * HH : 0);
  }
  const int hg32 = (2 * nb + wc) * 32;
#pragma unroll
  for (int hb = 0; hb < 2; ++hb) {
    const int hgl = hg32 + hb * 16 + l15;
    float bI = bA[hgl] + bB[hgl];
    float bF = bA[256 + hgl] + bB[256 + hgl];
    float bG = bA[512 + hgl] + bB[512 + hgl];
    float bO = bA[768 + hgl] + bB[768 + hgl];
#pragma unroll
    for (int mt = 0; mt < 2; ++mt) {
      const int rowb = mb * 128 + wr * 32 + mt * 16 + quad * 4;
#pragma unroll
      for (int r = 0; r < 4; ++r) {
        const size_t ix = (size_t)(rowb + r) * HH + hgl;
        float xi = acc[mt][0 + hb][r] + bI;
        float xf = acc[mt][2 + hb][r] + bF;
        float xg = acc[mt][4 + hb][r] + bG;
        float xo = acc[mt][6 + hb][r] + bO;
        float c_old = cbuf[ix];
        float cn = sigm(xf) * c_old + sigm(xi) * tanh_fast(xg);
        float hn = sigm(xo) * tanh_fast(cn);
        cbuf[ix] = cn;
        hout[ix] = f2bf(hn);
        if (hf) hf[ix] = hn;
        if (cf) cf[ix] = cn;
      }
    }
  }
}

// Output projection: out[m=t*B+b][o] = hs[m+B][:] . Wob[o][:] + bout[o]
// M=81920, N=16 (12 used), K=256. One 16x16 tile per wave.
__global__ __launch_bounds__(256) void out_gemm_mfma(
    const unsigned short* __restrict__ hs,
    const unsigned short* __restrict__ Wob,
    const float* __restrict__ bout,
    float* __restrict__ out) {
  const int tid = threadIdx.x;
  const int w = tid >> 6, lane = tid & 63, quad = lane >> 4, l15 = lane & 15;
  const int m0 = blockIdx.x * 64 + w * 16;
  const unsigned short* arow = hs + (size_t)(m0 + l15 + BB) * HH + quad * 8;
  const unsigned short* brow = Wob + l15 * HH + quad * 8;
  f32x4 acc = (f32x4){0.f, 0.f, 0.f, 0.f};
#pragma unroll
  for (int k0 = 0; k0 < 8; ++k0) {
    bf16x8 a = *(const bf16x8*)(arow + k0 * 32);
    bf16x8 b = *(const bf16x8*)(brow + k0 * 32);
    acc = __builtin_amdgcn_mfma_f32_16x16x32_bf16(a, b, acc, 0, 0, 0);
  }
  const int o = l15;
  if (o < OO) {
    float bv = bout[o];
#pragma unroll
    for (int r = 0; r < 4; ++r) {
      int m = m0 + quad * 4 + r;
      int b = m & (BB - 1);
      int t = m >> 13;
      out[((size_t)b * TT + t) * OO + o] = acc[r] + bv;
    }
  }
}

extern "C" void kernel_launch(void* const* d_in, const int* in_sizes, int n_in,
                              void* d_out, int out_size, void* d_ws, size_t ws_size,
                              hipStream_t stream) {
  const float* inputs = (const float*)d_in[0];
  const float* W_inp  = (const float*)d_in[1];
  const float* b_inp  = (const float*)d_in[2];
  const float* Wih0   = (const float*)d_in[3];
  const float* Whh0   = (const float*)d_in[4];
  const float* bih0   = (const float*)d_in[5];
  const float* bhh0   = (const float*)d_in[6];
  const float* Wih1   = (const float*)d_in[7];
  const float* Whh1   = (const float*)d_in[8];
  const float* bih1   = (const float*)d_in[9];
  const float* bhh1   = (const float*)d_in[10];
  const float* W_out  = (const float*)d_in[11];
  const float* b_out  = (const float*)d_in[12];
  float* out = (float*)d_out;

  char* ws = (char*)d_ws;
  size_t off = 0;
  auto alloc = [&](size_t bytes) {
    char* p = ws + off;
    off += (bytes + 255) & ~(size_t)255;
    return p;
  };
  unsigned short* xp  = (unsigned short*)alloc((size_t)81920 * HH * 2);
  unsigned short* Wib = (unsigned short*)alloc((size_t)256 * FP * 2);
  unsigned short* W0p = (unsigned short*)alloc((size_t)1024 * 512 * 2);
  unsigned short* W1p = (unsigned short*)alloc((size_t)1024 * 512 * 2);
  unsigned short* Wob = (unsigned short*)alloc((size_t)16 * HH * 2);
  unsigned short* h0s = (unsigned short*)alloc((size_t)2 * BB * HH * 2);
  unsigned short* hs  = (unsigned short*)alloc((size_t)(TT + 1) * BB * HH * 2);
  float* c0 = (float*)alloc((size_t)BB * HH * 4);
  float* c1 = (float*)alloc((size_t)BB * HH * 4);

  hipMemsetAsync(h0s, 0, (size_t)BB * HH * 2, stream);   // slot 0 only
  hipMemsetAsync(hs, 0, (size_t)BB * HH * 2, stream);    // slot 0 only
  hipMemsetAsync(c0, 0, (size_t)BB * HH * 4, stream);
  hipMemsetAsync(c1, 0, (size_t)BB * HH * 4, stream);

  {
    int nthr = 256 * 576 + 2 * 1024 * 512 + 16 * 256;
    conv_weights<<<(nthr + 255) / 256, 256, 0, stream>>>(W_inp, Wih0, Whh0, Wih1, Whh1,
                                                         W_out, Wib, W0p, W1p, Wob);
  }

  xp_gemm<<<640, 512, 0, stream>>>(inputs, Wib, b_inp, xp);

  float* hn_out = out + (size_t)BB * TT * OO;       // h_n [2][B][H]
  float* cn_out = hn_out + (size_t)2 * BB * HH;     // c_n [2][B][H]

  for (int p = 0; p <= TT; ++p) {
    step_pair<<<512, 512, 0, stream>>>(
        p, xp, W0p, W1p, bih0, bhh0, bih1, bhh1,
        h0s, hs, c0, c1, hn_out, cn_out);
  }

  out_gemm_mfma<<<1280, 256, 0, stream>>>(hs, Wob, b_out, out);
}